// Round 5
// baseline (317.751 us; speedup 1.0000x reference)
//
#include <hip/hip_runtime.h>
#include <math.h>

#define LRELU_ALPHA 0.2f
#define NEG_BIG -9000000000000000.0f

// d_ws layout (floats): [0,512) wa = W@a ; [512, 512+4096) Wf = bf16 W^T
#define WA_OFF 0
#define WF_OFF 512

typedef __attribute__((ext_vector_type(8))) short bf16x8;
typedef __attribute__((ext_vector_type(4))) float f32x4;

static __device__ inline unsigned short f2bf(float x) {
    unsigned int u = __float_as_uint(x);
    unsigned int r = (u + 0x7FFFu + ((u >> 16) & 1u)) >> 16;   // RNE
    return (unsigned short)r;
}

// -------------------------------------------------------------------------
// Kernel 0: prep. Blocks 0..31: Wf[n*128+k] = bf16(W[k][n]) (B-frag-ready
// transpose). Block 32: wa[gi*256 + j*128 + c] = sum_f W[c][f]*a[gi,j*64+f].
// -------------------------------------------------------------------------
__global__ __launch_bounds__(256) void gat_prep_kernel(
    const float* __restrict__ W, const float* __restrict__ a,
    float* __restrict__ ws)
{
    const int tid = threadIdx.x;
    if (blockIdx.x < 32) {
        short* wf = (short*)(ws + WF_OFF);
        const int o = blockIdx.x * 256 + tid;
        const int n = o >> 7, k = o & 127;
        wf[o] = (short)f2bf(W[k * 64 + n]);
    } else {
        float* wa = ws + WA_OFF;
        for (int idx = tid; idx < 512; idx += 256) {
            const int gi = idx >> 8, j = (idx >> 7) & 1, c = idx & 127;
            const float* Wr = W + c * 64;
            const float* ar = a + gi * 128 + j * 64;
            float s = 0.f;
#pragma unroll
            for (int f = 0; f < 64; ++f) s = fmaf(Wr[f], ar[f], s);
            wa[idx] = s;
        }
    }
}

// -------------------------------------------------------------------------
// Fused main: out = elu( (Att @ h) @ W ), att computed in-block.
// Block = 4 consecutive bn (same b), 4 waves, 8 blocks/CU (256,8).
// Att phase (wave w <-> n0+w, halves split gi): redundant per-b compute; the
// att-source rows (b=0/1, 12.6 MB) are L2/L3-resident so HBM delta ~0.
// attl is wave-private -> NO barrier between att and phase 1.
// Phase 1: wave w builds P rows [12w,12w+12) for bn0+w (att via wave-uniform
// LDS broadcast). One sync. Phase 2: wave w = output cols [16w,16w+16),
// 3 mt x 4 ks mfma_f32_16x16x32_bf16 vs global Wf (L2-hot). Elu store.
// hv loads AFTER att phase: keeps peak VGPR under the (256,8)=64 bound
// (att temps die before hv+acc go live).
// -------------------------------------------------------------------------
#define PSTR 136
__global__ __launch_bounds__(256, 8) void gat_main_mfma(
    const float* __restrict__ h, const int* __restrict__ adj,
    const float* __restrict__ ws, float* __restrict__ out)
{
    __shared__ __align__(16) short Pl[48 * PSTR];    // 13056 B
    __shared__ __align__(16) float attl[288];        // [gi][nn][36], 1152 B

    const int tid  = threadIdx.x;
    const int warp = tid >> 6;
    const int lane = tid & 63;
    const int half = lane >> 5;
    const int li   = lane & 31;
    const int bn0  = blockIdx.x * 4;
    const int n0   = bn0 & 2047;        // blocks never straddle b (2048%4==0)
    const int gi   = half;              // half-wave splits the two graphs

    // ---- att phase: wave w computes att(gi, n0+w) for both gi ----
    {
        const int n = n0 + warp;
        const float* wa = ws + WA_OFF;
        const f32x4 w1 = *(const f32x4*)(wa + gi * 256 + li * 4);
        const f32x4 w2 = *(const f32x4*)(wa + gi * 256 + 128 + li * 4);
        // source rows: b=gi, k = gi*6+q (reused across all 16 b -> cache-hot)
        const float* hs = h + (size_t)(gi * 2048 + n) * 1536 + gi * 6 * 128 + li * 4;
        float t1[6], t2[6];
#pragma unroll
        for (int q = 0; q < 6; ++q) {
            const f32x4 hq = *(const f32x4*)(hs + q * 128);
            t1[q] = hq[0] * w1[0] + hq[1] * w1[1] + hq[2] * w1[2] + hq[3] * w1[3];
            t2[q] = hq[0] * w2[0] + hq[1] * w2[1] + hq[2] * w2[2] + hq[3] * w2[3];
        }
#pragma unroll
        for (int off = 16; off > 0; off >>= 1) {
#pragma unroll
            for (int q = 0; q < 6; ++q) {
                t1[q] += __shfl_xor(t1[q], off, 64);   // stays within 32-half
                t2[q] += __shfl_xor(t2[q], off, 64);
            }
        }
        if (li < 6) {
            const int p = li;
            float s1p = t1[0];
#pragma unroll
            for (int q = 1; q < 6; ++q) { if (p == q) s1p = t1[q]; }
            float row[6];
            float mx = -3.0e38f;
#pragma unroll
            for (int q = 0; q < 6; ++q) {
                float e = s1p + t2[q];
                e = (e > 0.f) ? e : (LRELU_ALPHA * e);
                const int ad = adj[gi * 36 + p * 6 + q];
                const float m = (ad > 0) ? e : NEG_BIG;
                row[q] = m;
                mx = fmaxf(mx, m);
            }
            float sum = 0.f;
#pragma unroll
            for (int q = 0; q < 6; ++q) {
                row[q] = expf(row[q] - mx);
                sum += row[q];
            }
            const float inv = 1.f / sum;
#pragma unroll
            for (int q = 0; q < 6; ++q)
                attl[gi * 144 + warp * 36 + p * 6 + q] = row[q] * inv;
        }
    }
    // attl is wave-private (wave w writes+reads only [.,w,.]): no barrier.

    // ---- phase 1: wave w builds P rows for bn = bn0 + w ----
    const int bn = bn0 + warp;
    const float* hb = h + (size_t)bn * 1536 + gi * 6 * 128 + li * 4;
    f32x4 hv[6];
#pragma unroll
    for (int r = 0; r < 6; ++r)
        hv[r] = __builtin_nontemporal_load((const f32x4*)(hb + r * 128));

    const float* av = attl + gi * 144 + warp * 36;
#pragma unroll
    for (int p = 0; p < 6; ++p) {
        float ax = 0.f, ay = 0.f, az = 0.f, aw = 0.f;
#pragma unroll
        for (int q = 0; q < 6; ++q) {
            const float apq = av[p * 6 + q];   // wave-uniform LDS broadcast
            const f32x4 hq = hv[q];
            ax = fmaf(apq, hq[0], ax);
            ay = fmaf(apq, hq[1], ay);
            az = fmaf(apq, hq[2], az);
            aw = fmaf(apq, hq[3], aw);
        }
        const int row = warp * 12 + gi * 6 + p;
        ushort4 pk;
        pk.x = f2bf(ax); pk.y = f2bf(ay);
        pk.z = f2bf(az); pk.w = f2bf(aw);
        *(ushort4*)(Pl + row * PSTR + li * 4) = pk;
    }

    __syncthreads();                     // P ready for all waves

    // ---- phase 2: wave w -> output cols [16w,16w+16), 3 mt x 4 ks ----
    const short* wf = (const short*)(ws + WF_OFF);
    const int col  = lane & 15;
    const int quad = lane >> 4;
    f32x4 acc[3];
#pragma unroll
    for (int mt = 0; mt < 3; ++mt) acc[mt] = (f32x4){0.f, 0.f, 0.f, 0.f};

#pragma unroll
    for (int ks = 0; ks < 4; ++ks) {
        const bf16x8 bfr = *(const bf16x8*)(wf + (warp * 16 + col) * 128 + ks * 32 + quad * 8);
#pragma unroll
        for (int mt = 0; mt < 3; ++mt) {
            const bf16x8 afr = *(const bf16x8*)(Pl + (mt * 16 + col) * PSTR + ks * 32 + quad * 8);
            acc[mt] = __builtin_amdgcn_mfma_f32_16x16x32_bf16(afr, bfr, acc[mt], 0, 0, 0);
        }
    }

    // ---- epilogue: elu + store. C/D: col=lane&15, row=quad*4+reg ----
    float* ob = out + (size_t)bn0 * 768 + warp * 16 + col;
#pragma unroll
    for (int mt = 0; mt < 3; ++mt)
#pragma unroll
        for (int r = 0; r < 4; ++r) {
            const int row = mt * 16 + quad * 4 + r;
            float v = acc[mt][r];
            v = (v > 0.f) ? v : (expf(v) - 1.f);
            __builtin_nontemporal_store(v, ob + row * 64);
        }
}

extern "C" void kernel_launch(void* const* d_in, const int* in_sizes, int n_in,
                              void* d_out, int out_size, void* d_ws, size_t ws_size,
                              hipStream_t stream) {
    const float* h   = (const float*)d_in[0];   // (16,2048,12,128) fp32
    const int*   adj = (const int*)d_in[1];     // (2,6,6) int32
    const float* W   = (const float*)d_in[2];   // (128,64) fp32
    const float* a   = (const float*)d_in[3];   // (2,128,1) fp32
    float* out = (float*)d_out;                 // (16,2048,12,64) fp32
    float* ws  = (float*)d_ws;

    hipLaunchKernelGGL(gat_prep_kernel, dim3(33), dim3(256), 0, stream, W, a, ws);
    hipLaunchKernelGGL(gat_main_mfma, dim3(8192), dim3(256), 0, stream, h, adj, ws, out);
}